// Round 10
// baseline (152.847 us; speedup 1.0000x reference)
//
#include <hip/hip_runtime.h>
#include <hip/hip_bf16.h>

#define F 256
#define NF4 (F / 4)
#define GEMM_ROWS 16
#define BUCKET 128
#define PW_THREADS (3 * 8 * 16 * 64)   // 24576

typedef short v8s __attribute__((ext_vector_type(8)));
typedef float v4f __attribute__((ext_vector_type(4)));

__device__ __forceinline__ unsigned short f2bf_rtne(float f) {
    unsigned int u = __float_as_uint(f);
    u += 0x7FFFu + ((u >> 16) & 1u);
    return (unsigned short)(u >> 16);
}
__device__ __forceinline__ float bflo(unsigned int u) { return __uint_as_float(u << 16); }
__device__ __forceinline__ float bfhi(unsigned int u) { return __uint_as_float(u & 0xFFFF0000u); }

// ============ fused: bucket-scatter (count+placement in one atomic) + pack_x + pack_w ====
// counts pre-zeroed. bucket[d*128+pos] = {src, val}.
// xpack: [mtile][ks][lane][j] bf16 = x[mtile*16+(lane&15)][ks*32+(lane>>4)*8+j]
// wpack: [mat][ks][ntile][lane][j] bf16 = W[ks*32+(lane>>4)*8+j][ntile*16+(lane&15)]
__global__ __launch_bounds__(256) void pack_bucket(const float* __restrict__ X,
                                                   const float* __restrict__ W1,
                                                   const float* __restrict__ W2,
                                                   const float* __restrict__ W3,
                                                   const int* __restrict__ src,
                                                   const int* __restrict__ dst,
                                                   const float* __restrict__ vals,
                                                   int* __restrict__ counts,
                                                   int2* __restrict__ bucket,
                                                   short* __restrict__ xpack,
                                                   short* __restrict__ wpack,
                                                   int MT, int E) {
    const int t = blockIdx.x * 256 + threadIdx.x;
    if (t < E) {
        const int d = dst[t];
        const int pos = atomicAdd(&counts[d], 1);
        if (pos < BUCKET)   // memory-safety only; never triggers for this graph (max deg ~56)
            bucket[((size_t)d << 7) + pos] = make_int2(src[t], __float_as_int(vals[t]));
        return;
    }
    const int u = t - E;
    const int PX = MT * 8 * 64;
    if (u < PX) {
        const int lane = u & 63;
        const int ks = (u >> 6) & 7;
        const int mtile = u >> 9;
        const int row = mtile * 16 + (lane & 15);
        const int kbase = ks * 32 + ((lane >> 4) << 3);
        const float* srcp = X + (size_t)row * F + kbase;
        v8s o;
#pragma unroll
        for (int j = 0; j < 8; ++j) o[j] = (short)f2bf_rtne(srcp[j]);
        ((v8s*)xpack)[u] = o;
    } else if (u < PX + PW_THREADS) {
        const int tw = u - PX;
        const int lane = tw & 63;
        const int nt = (tw >> 6) & 15;
        const int ks = (tw >> 10) & 7;
        const int mat = tw >> 13;
        const float* W = (mat == 0) ? W1 : (mat == 1 ? W2 : W3);
        const int col = nt * 16 + (lane & 15);
        const int kbase = ks * 32 + ((lane >> 4) << 3);
        v8s o;
#pragma unroll
        for (int j = 0; j < 8; ++j) o[j] = (short)f2bf_rtne(W[(size_t)(kbase + j) * F + col]);
        ((v8s*)wpack)[tw] = o;
    }
}

// ============ MFMA GEMM: H1 fp32 (=out, row-major), H2/H3 bf16 in HALF-MAJOR layout ====
// half-major: H[half][row][128] with half = col>>7 — matches the half-split SPMM passes.
__global__ __launch_bounds__(256) void mfma_gemm3(const short* __restrict__ xpack,
                                                  const short* __restrict__ wpack,
                                                  float* __restrict__ H1,
                                                  unsigned short* __restrict__ H2b,
                                                  unsigned short* __restrict__ H3b,
                                                  int MT) {
    const int wid = (blockIdx.x * 256 + threadIdx.x) >> 6;
    const int lane = threadIdx.x & 63;
    const int per_mat = MT * 4;
    if (wid >= 3 * per_mat) return;
    const int mat = wid / per_mat;
    const int rem = wid - mat * per_mat;
    const int mtile = rem >> 2;
    const int ntq = rem & 3;

    const v8s* xa = (const v8s*)xpack + (size_t)mtile * (8 * 64) + lane;
    const v8s* wb = (const v8s*)wpack + (size_t)mat * (8 * 16 * 64) + ntq * (4 * 64) + lane;

    v8s a[8];
#pragma unroll
    for (int ks = 0; ks < 8; ++ks) a[ks] = xa[ks * 64];

    v4f acc[4];
#pragma unroll
    for (int nt = 0; nt < 4; ++nt) { v4f z = {0.f, 0.f, 0.f, 0.f}; acc[nt] = z; }

#pragma unroll
    for (int ks = 0; ks < 8; ++ks)
#pragma unroll
        for (int nt = 0; nt < 4; ++nt) {
            const v8s b = wb[ks * (16 * 64) + nt * 64];
            acc[nt] = __builtin_amdgcn_mfma_f32_16x16x32_bf16(a[ks], b, acc[nt], 0, 0, 0);
        }

    const int r0 = mtile * 16 + ((lane >> 4) << 2);   // C/D: row=(lane>>4)*4+reg
    const int c0 = ntq * 64 + (lane & 15);            //      col=lane&15
    if (mat == 0) {
#pragma unroll
        for (int nt = 0; nt < 4; ++nt)
#pragma unroll
            for (int reg = 0; reg < 4; ++reg)
                H1[(size_t)(r0 + reg) * F + c0 + nt * 16] = acc[nt][reg];
    } else {
        unsigned short* H = (mat == 1) ? H2b : H3b;
        const int NN = MT << 4;
#pragma unroll
        for (int nt = 0; nt < 4; ++nt) {
            const int col = c0 + nt * 16;
            unsigned short* Hh = H + (size_t)(col >> 7) * ((size_t)NN * 128);
#pragma unroll
            for (int reg = 0; reg < 4; ++reg)
                Hh[(size_t)(r0 + reg) * 128 + (col & 127)] = f2bf_rtne(acc[nt][reg]);
        }
    }
}

// ============ SPMM: sequential half-feature passes (no XCD-mapping assumption) ============
// Dispatch covers ALL rows but only 128 features (half). Gather working set =
// N*128*2B = 2.56 MB < 4 MiB per-XCD L2 -> gathers L2-hit after compulsory misses,
// on every XCD regardless of block placement. hb is half-major base; lane owns
// 1 uint (2 bf16). Bucket/addv loads NT (streamed / read-once); FINAL store NT;
// intermediate bf16 stores REGULAR (next pass's gather set).
// ADD_MODE: 0=none, 1=fp32 row-major addv, 2=bf16 half-major addv.
// FINAL: relu(acc/3) -> fp32 row-major; else bf16 half-major.
template <int ADD_MODE, bool FINAL>
__global__ __launch_bounds__(256) void spmm_hseq(const unsigned int* __restrict__ hb,
                                                 const int* __restrict__ counts,
                                                 const int2* __restrict__ bucket,
                                                 const void* __restrict__ addv,
                                                 void* __restrict__ outp,
                                                 int N, int half) {
    const int row = (blockIdx.x * 256 + threadIdx.x) >> 6;
    const int lane = threadIdx.x & 63;
    if (row >= N) return;

    const unsigned int* hbh = hb + (size_t)half * ((size_t)N * 64);

    int deg = counts[row];
    deg = (deg > BUCKET) ? BUCKET : deg;
    const unsigned long long* bk =
        (const unsigned long long*)(bucket + ((size_t)row << 7));

    float2 acc;
    if (ADD_MODE == 1) {
        const double ad = __builtin_nontemporal_load(
            (const double*)addv + (size_t)row * 128 + half * 64 + lane);
        const unsigned long long ab = __double_as_longlong(ad);
        acc.x = __uint_as_float((unsigned int)ab);
        acc.y = __uint_as_float((unsigned int)(ab >> 32));
    } else if (ADD_MODE == 2) {
        const unsigned int a = __builtin_nontemporal_load(
            (const unsigned int*)addv + (size_t)half * ((size_t)N * 64) +
            (size_t)row * 64 + lane);
        acc.x = bflo(a); acc.y = bfhi(a);
    } else {
        acc.x = 0.f; acc.y = 0.f;
    }

    int k = 0;
    for (; k + 8 <= deg; k += 8) {
        unsigned long long p[8];
        unsigned int g[8];
#pragma unroll
        for (int j = 0; j < 8; ++j) p[j] = __builtin_nontemporal_load(&bk[k + j]);
#pragma unroll
        for (int j = 0; j < 8; ++j)
            g[j] = hbh[((size_t)(unsigned int)p[j]) * 64 + lane];
#pragma unroll
        for (int j = 0; j < 8; ++j) {
            const float v = __uint_as_float((unsigned int)(p[j] >> 32));
            acc.x = fmaf(bflo(g[j]), v, acc.x);
            acc.y = fmaf(bfhi(g[j]), v, acc.y);
        }
    }
    for (; k < deg; ++k) {
        const unsigned long long p = __builtin_nontemporal_load(&bk[k]);
        const unsigned int g = hbh[((size_t)(unsigned int)p) * 64 + lane];
        const float v = __uint_as_float((unsigned int)(p >> 32));
        acc.x = fmaf(bflo(g), v, acc.x);
        acc.y = fmaf(bfhi(g), v, acc.y);
    }

    if (FINAL) {
        const float s = 1.0f / 3.0f;
        acc.x = fmaxf(acc.x * s, 0.f);
        acc.y = fmaxf(acc.y * s, 0.f);
        const unsigned long long ob =
            (unsigned long long)__float_as_uint(acc.x) |
            ((unsigned long long)__float_as_uint(acc.y) << 32);
        __builtin_nontemporal_store(__longlong_as_double(ob),
                                    (double*)outp + (size_t)row * 128 + half * 64 + lane);
    } else {
        const unsigned int o = (unsigned int)f2bf_rtne(acc.x) |
                               ((unsigned int)f2bf_rtne(acc.y) << 16);
        ((unsigned int*)outp)[(size_t)half * ((size_t)N * 64) +
                              (size_t)row * 64 + lane] = o;
    }
}

// ============ fallback tier: fp32 vector GEMM + fp32 bucket SPMM ============
__global__ __launch_bounds__(256) void bucket_only(const int* __restrict__ src,
                                                   const int* __restrict__ dst,
                                                   const float* __restrict__ vals,
                                                   int* __restrict__ counts,
                                                   int2* __restrict__ bucket, int E) {
    const int t = blockIdx.x * 256 + threadIdx.x;
    if (t < E) {
        const int d = dst[t];
        const int pos = atomicAdd(&counts[d], 1);
        if (pos < BUCKET)
            bucket[((size_t)d << 7) + pos] = make_int2(src[t], __float_as_int(vals[t]));
    }
}

__global__ __launch_bounds__(256) void gemm3_xw(const float* __restrict__ X,
                                                const float* __restrict__ W1,
                                                const float* __restrict__ W2,
                                                const float* __restrict__ W3,
                                                float* __restrict__ H1,
                                                float* __restrict__ H2,
                                                float* __restrict__ H3) {
    __shared__ float xs[GEMM_ROWS * F];
    const int tid = threadIdx.x;
    const int row0 = blockIdx.x * GEMM_ROWS;
#pragma unroll
    for (int r = 0; r < GEMM_ROWS; ++r)
        xs[r * F + tid] = X[(size_t)(row0 + r) * F + tid];
    __syncthreads();

    float a1[GEMM_ROWS], a2[GEMM_ROWS], a3[GEMM_ROWS];
#pragma unroll
    for (int r = 0; r < GEMM_ROWS; ++r) { a1[r] = 0.f; a2[r] = 0.f; a3[r] = 0.f; }

    const float4* xs4 = (const float4*)xs;
    for (int kk = 0; kk < F; kk += 4) {
        float w1v[4], w2v[4], w3v[4];
#pragma unroll
        for (int j = 0; j < 4; ++j) {
            w1v[j] = W1[(size_t)(kk + j) * F + tid];
            w2v[j] = W2[(size_t)(kk + j) * F + tid];
            w3v[j] = W3[(size_t)(kk + j) * F + tid];
        }
#pragma unroll
        for (int r = 0; r < GEMM_ROWS; ++r) {
            const float4 xv = xs4[r * NF4 + (kk >> 2)];
            a1[r] = fmaf(xv.x, w1v[0], a1[r]); a1[r] = fmaf(xv.y, w1v[1], a1[r]);
            a1[r] = fmaf(xv.z, w1v[2], a1[r]); a1[r] = fmaf(xv.w, w1v[3], a1[r]);
            a2[r] = fmaf(xv.x, w2v[0], a2[r]); a2[r] = fmaf(xv.y, w2v[1], a2[r]);
            a2[r] = fmaf(xv.z, w2v[2], a2[r]); a2[r] = fmaf(xv.w, w2v[3], a2[r]);
            a3[r] = fmaf(xv.x, w3v[0], a3[r]); a3[r] = fmaf(xv.y, w3v[1], a3[r]);
            a3[r] = fmaf(xv.z, w3v[2], a3[r]); a3[r] = fmaf(xv.w, w3v[3], a3[r]);
        }
    }
#pragma unroll
    for (int r = 0; r < GEMM_ROWS; ++r) {
        H1[(size_t)(row0 + r) * F + tid] = a1[r];
        H2[(size_t)(row0 + r) * F + tid] = a2[r];
        H3[(size_t)(row0 + r) * F + tid] = a3[r];
    }
}

// fp32 bucket SPMM (fallback): addv/out4 may alias row-locally — not restrict.
__global__ __launch_bounds__(256) void spmm_f32(const float4* __restrict__ h4,
                                                const int* __restrict__ counts,
                                                const int2* __restrict__ bucket,
                                                const float4* addv,
                                                float4* out4,
                                                int N, int final_mode) {
    const int row = (blockIdx.x * 256 + threadIdx.x) >> 6;
    const int lane = threadIdx.x & 63;
    if (row >= N) return;

    int deg = counts[row];
    deg = (deg > BUCKET) ? BUCKET : deg;
    const int2* bk = bucket + ((size_t)row << 7);

    float4 acc = addv ? addv[(size_t)row * 64 + lane]
                      : make_float4(0.f, 0.f, 0.f, 0.f);

    int k = 0;
    for (; k + 4 <= deg; k += 4) {
        const int2 p0 = bk[k + 0];
        const int2 p1 = bk[k + 1];
        const int2 p2 = bk[k + 2];
        const int2 p3 = bk[k + 3];
        const float4 h0 = h4[(size_t)p0.x * 64 + lane];
        const float4 h1 = h4[(size_t)p1.x * 64 + lane];
        const float4 h2 = h4[(size_t)p2.x * 64 + lane];
        const float4 h3 = h4[(size_t)p3.x * 64 + lane];
        const float v0 = __int_as_float(p0.y), v1 = __int_as_float(p1.y);
        const float v2 = __int_as_float(p2.y), v3 = __int_as_float(p3.y);
        acc.x = fmaf(h0.x, v0, acc.x); acc.y = fmaf(h0.y, v0, acc.y);
        acc.z = fmaf(h0.z, v0, acc.z); acc.w = fmaf(h0.w, v0, acc.w);
        acc.x = fmaf(h1.x, v1, acc.x); acc.y = fmaf(h1.y, v1, acc.y);
        acc.z = fmaf(h1.z, v1, acc.z); acc.w = fmaf(h1.w, v1, acc.w);
        acc.x = fmaf(h2.x, v2, acc.x); acc.y = fmaf(h2.y, v2, acc.y);
        acc.z = fmaf(h2.z, v2, acc.z); acc.w = fmaf(h2.w, v2, acc.w);
        acc.x = fmaf(h3.x, v3, acc.x); acc.y = fmaf(h3.y, v3, acc.y);
        acc.z = fmaf(h3.z, v3, acc.z); acc.w = fmaf(h3.w, v3, acc.w);
    }
    for (; k < deg; ++k) {
        const int2 p = bk[k];
        const float v = __int_as_float(p.y);
        const float4 hv = h4[(size_t)p.x * 64 + lane];
        acc.x = fmaf(hv.x, v, acc.x); acc.y = fmaf(hv.y, v, acc.y);
        acc.z = fmaf(hv.z, v, acc.z); acc.w = fmaf(hv.w, v, acc.w);
    }

    if (final_mode) {
        const float s = 1.0f / 3.0f;
        acc.x = fmaxf(acc.x * s, 0.f);
        acc.y = fmaxf(acc.y * s, 0.f);
        acc.z = fmaxf(acc.z * s, 0.f);
        acc.w = fmaxf(acc.w * s, 0.f);
    }
    out4[(size_t)row * 64 + lane] = acc;
}

extern "C" void kernel_launch(void* const* d_in, const int* in_sizes, int n_in,
                              void* d_out, int out_size, void* d_ws, size_t ws_size,
                              hipStream_t stream) {
    const float* x     = (const float*)d_in[0];
    const float* Avals = (const float*)d_in[1];
    const float* W1    = (const float*)d_in[2];
    const float* W2    = (const float*)d_in[3];
    const float* W3    = (const float*)d_in[4];
    const int*   esrc  = (const int*)d_in[5];
    const int*   edst  = (const int*)d_in[6];
    float*       out   = (float*)d_out;

    const int N = in_sizes[0] / F;   // 10000
    const int E = in_sizes[5];       // 320000

    const size_t mat_elems = (size_t)N * F;
    const int spmm_grid  = ((size_t)N * 64 + 255) / 256;     // one wave per row
    const int gemm_grid  = (N + GEMM_ROWS - 1) / GEMM_ROWS;
    const int MT = N / 16;

    const size_t bucket_bytes = (size_t)N * BUCKET * sizeof(int2);   // 10.24 MB

    const size_t need_main =
        bucket_bytes + 4 * mat_elems * sizeof(short) +
        (size_t)3 * F * F * sizeof(short) + (size_t)(N + 16) * sizeof(int) + 64;
    const size_t need_fb =
        bucket_bytes + 2 * mat_elems * sizeof(float) + (size_t)(N + 16) * sizeof(int) + 64;

    if ((N % 16 == 0) && ws_size >= need_main) {
        int2*           bucket = (int2*)d_ws;
        unsigned short* hb0    = (unsigned short*)(bucket + (size_t)N * BUCKET);  // h3 / t2
        unsigned short* hb1    = hb0 + mat_elems;                                  // t1
        unsigned short* hb2    = hb1 + mat_elems;                                  // h2
        short*          xpack  = (short*)(hb2 + mat_elems);
        short*          wpack  = xpack + mat_elems;
        int*            counts = (int*)(wpack + (size_t)3 * F * F);

        const int PX = MT * 8 * 64;
        const int pc_threads = E + PX + PW_THREADS;

        hipMemsetAsync(counts, 0, (size_t)N * sizeof(int), stream);
        pack_bucket<<<(pc_threads + 255) / 256, 256, 0, stream>>>(
            x, W1, W2, W3, esrc, edst, Avals, counts, bucket, xpack, wpack, MT, E);

        // h1 -> out (fp32 row-major), h2 -> hb2, h3 -> hb0 (bf16 half-major)
        const int gw = 3 * MT * 4;
        mfma_gemm3<<<(gw * 64 + 255) / 256, 256, 0, stream>>>(xpack, wpack,
                                                              out, hb2, hb0, MT);

        // t1 = A h3 + h2 -> hb1 (two sequential half-feature dispatches per pass)
        spmm_hseq<2, false><<<spmm_grid, 256, 0, stream>>>(
            (const unsigned int*)hb0, counts, bucket, hb2, hb1, N, 0);
        spmm_hseq<2, false><<<spmm_grid, 256, 0, stream>>>(
            (const unsigned int*)hb0, counts, bucket, hb2, hb1, N, 1);
        // t2 = A t1 + h1 -> hb0
        spmm_hseq<1, false><<<spmm_grid, 256, 0, stream>>>(
            (const unsigned int*)hb1, counts, bucket, out, hb0, N, 0);
        spmm_hseq<1, false><<<spmm_grid, 256, 0, stream>>>(
            (const unsigned int*)hb1, counts, bucket, out, hb0, N, 1);
        // out = relu(A t2 / 3) -> fp32
        spmm_hseq<0, true><<<spmm_grid, 256, 0, stream>>>(
            (const unsigned int*)hb0, counts, bucket, nullptr, out, N, 0);
        spmm_hseq<0, true><<<spmm_grid, 256, 0, stream>>>(
            (const unsigned int*)hb0, counts, bucket, nullptr, out, N, 1);
    } else if (ws_size >= need_fb) {
        int2*  bucket = (int2*)d_ws;
        float* h2buf  = (float*)(bucket + (size_t)N * BUCKET);
        float* h3buf  = h2buf + mat_elems;
        int*   counts = (int*)(h3buf + mat_elems);

        hipMemsetAsync(counts, 0, (size_t)N * sizeof(int), stream);
        bucket_only<<<(E + 255) / 256, 256, 0, stream>>>(esrc, edst, Avals,
                                                         counts, bucket, E);

        gemm3_xw<<<gemm_grid, 256, 0, stream>>>(x, W1, W2, W3, out, h2buf, h3buf);

        spmm_f32<<<spmm_grid, 256, 0, stream>>>((const float4*)h3buf, counts, bucket,
                                                (const float4*)h2buf, (float4*)h2buf, N, 0);
        spmm_f32<<<spmm_grid, 256, 0, stream>>>((const float4*)h2buf, counts, bucket,
                                                (const float4*)out, (float4*)h3buf, N, 0);
        spmm_f32<<<spmm_grid, 256, 0, stream>>>((const float4*)h3buf, counts, bucket,
                                                nullptr, (float4*)out, N, 1);
    }
}

// Round 11
// 126.055 us; speedup vs baseline: 1.2125x; 1.2125x over previous
//
#include <hip/hip_runtime.h>
#include <hip/hip_bf16.h>

#define F 256
#define NF4 (F / 4)
#define GEMM_ROWS 16
#define BUCKET 128
#define PW_THREADS (3 * 8 * 16 * 64)   // 24576

typedef short v8s __attribute__((ext_vector_type(8)));
typedef float v4f __attribute__((ext_vector_type(4)));

__device__ __forceinline__ unsigned short f2bf_rtne(float f) {
    unsigned int u = __float_as_uint(f);
    u += 0x7FFFu + ((u >> 16) & 1u);
    return (unsigned short)(u >> 16);
}
__device__ __forceinline__ float bflo(unsigned int u) { return __uint_as_float(u << 16); }
__device__ __forceinline__ float bfhi(unsigned int u) { return __uint_as_float(u & 0xFFFF0000u); }

// ============ fused: bucket-scatter (count+placement in one atomic) + pack_w ============
// counts pre-zeroed. bucket[d*128+pos] = {src, val}.
// wpack: [mat][ks][ntile][lane][j] bf16 = W[ks*32+(lane>>4)*8+j][ntile*16+(lane&15)]
// (x is NOT packed — the MFMA kernel reads its A-fragments directly from x.)
__global__ __launch_bounds__(256) void bucket_packw(const int* __restrict__ src,
                                                    const int* __restrict__ dst,
                                                    const float* __restrict__ vals,
                                                    const float* __restrict__ W1,
                                                    const float* __restrict__ W2,
                                                    const float* __restrict__ W3,
                                                    int* __restrict__ counts,
                                                    int2* __restrict__ bucket,
                                                    short* __restrict__ wpack,
                                                    int E) {
    const int t = blockIdx.x * 256 + threadIdx.x;
    if (t < E) {
        const int d = dst[t];
        const int pos = atomicAdd(&counts[d], 1);
        if (pos < BUCKET)   // memory-safety only; never triggers (max deg ~56)
            bucket[((size_t)d << 7) + pos] = make_int2(src[t], __float_as_int(vals[t]));
        return;
    }
    const int u = t - E;
    if (u < PW_THREADS) {
        const int lane = u & 63;
        const int nt = (u >> 6) & 15;
        const int ks = (u >> 10) & 7;
        const int mat = u >> 13;
        const float* W = (mat == 0) ? W1 : (mat == 1 ? W2 : W3);
        const int col = nt * 16 + (lane & 15);
        const int kbase = ks * 32 + ((lane >> 4) << 3);
        v8s o;
#pragma unroll
        for (int j = 0; j < 8; ++j) o[j] = (short)f2bf_rtne(W[(size_t)(kbase + j) * F + col]);
        ((v8s*)wpack)[u] = o;
    }
}

// ============ MFMA GEMM: A-fragments read DIRECTLY from x (contiguous float8/lane),
//              converted to bf16 in-register. H1 fp32 (=out), H2 bf16, H3 bf16. ============
__global__ __launch_bounds__(256) void mfma_gemm3(const float* __restrict__ X,
                                                  const short* __restrict__ wpack,
                                                  float* __restrict__ H1,
                                                  unsigned short* __restrict__ H2b,
                                                  unsigned short* __restrict__ H3b,
                                                  int MT) {
    const int wid = (blockIdx.x * 256 + threadIdx.x) >> 6;
    const int lane = threadIdx.x & 63;
    const int per_mat = MT * 4;
    if (wid >= 3 * per_mat) return;
    const int mat = wid / per_mat;
    const int rem = wid - mat * per_mat;
    const int mtile = rem >> 2;
    const int ntq = rem & 3;

    // A: x[mtile*16 + (lane&15)][ks*32 + (lane>>4)*8 + j], j=0..7 -> contiguous
    const float* xrow = X + (size_t)(mtile * 16 + (lane & 15)) * F + ((lane >> 4) << 3);
    v8s a[8];
#pragma unroll
    for (int ks = 0; ks < 8; ++ks) {
        const float4 f0 = *(const float4*)(xrow + ks * 32);
        const float4 f1 = *(const float4*)(xrow + ks * 32 + 4);
        v8s av;
        av[0] = (short)f2bf_rtne(f0.x); av[1] = (short)f2bf_rtne(f0.y);
        av[2] = (short)f2bf_rtne(f0.z); av[3] = (short)f2bf_rtne(f0.w);
        av[4] = (short)f2bf_rtne(f1.x); av[5] = (short)f2bf_rtne(f1.y);
        av[6] = (short)f2bf_rtne(f1.z); av[7] = (short)f2bf_rtne(f1.w);
        a[ks] = av;
    }

    const v8s* wb = (const v8s*)wpack + (size_t)mat * (8 * 16 * 64) + ntq * (4 * 64) + lane;

    v4f acc[4];
#pragma unroll
    for (int nt = 0; nt < 4; ++nt) { v4f z = {0.f, 0.f, 0.f, 0.f}; acc[nt] = z; }

#pragma unroll
    for (int ks = 0; ks < 8; ++ks)
#pragma unroll
        for (int nt = 0; nt < 4; ++nt) {
            const v8s b = wb[ks * (16 * 64) + nt * 64];
            acc[nt] = __builtin_amdgcn_mfma_f32_16x16x32_bf16(a[ks], b, acc[nt], 0, 0, 0);
        }

    const int r0 = mtile * 16 + ((lane >> 4) << 2);   // C/D: row=(lane>>4)*4+reg
    const int c0 = ntq * 64 + (lane & 15);            //      col=lane&15
    if (mat == 0) {
#pragma unroll
        for (int nt = 0; nt < 4; ++nt)
#pragma unroll
            for (int reg = 0; reg < 4; ++reg)
                H1[(size_t)(r0 + reg) * F + c0 + nt * 16] = acc[nt][reg];
    } else {
        unsigned short* H = (mat == 1) ? H2b : H3b;
#pragma unroll
        for (int nt = 0; nt < 4; ++nt)
#pragma unroll
            for (int reg = 0; reg < 4; ++reg)
                H[(size_t)(r0 + reg) * F + c0 + nt * 16] = f2bf_rtne(acc[nt][reg]);
    }
}

// ============ SPMM: one wave per row, bf16 gathers (512B/wave), unroll-8 — R7 proven ====
// ADD_MODE: 0=none, 1=fp32 addv, 2=bf16 addv. FINAL: relu(acc/3)->fp32, else bf16.
template <int ADD_MODE, bool FINAL>
__global__ __launch_bounds__(256) void spmm_bf(const uint2* __restrict__ hb,
                                               const int* __restrict__ counts,
                                               const int2* __restrict__ bucket,
                                               const void* __restrict__ addv,
                                               void* __restrict__ outp, int N) {
    const int row = (blockIdx.x * 256 + threadIdx.x) >> 6;
    const int lane = threadIdx.x & 63;
    if (row >= N) return;

    int deg = counts[row];
    deg = (deg > BUCKET) ? BUCKET : deg;
    const int2* bk = bucket + ((size_t)row << 7);

    float4 acc;
    if (ADD_MODE == 1) {
        acc = ((const float4*)addv)[(size_t)row * 64 + lane];
    } else if (ADD_MODE == 2) {
        const uint2 a = ((const uint2*)addv)[(size_t)row * 64 + lane];
        acc = make_float4(bflo(a.x), bfhi(a.x), bflo(a.y), bfhi(a.y));
    } else {
        acc = make_float4(0.f, 0.f, 0.f, 0.f);
    }

    int k = 0;
    for (; k + 8 <= deg; k += 8) {
        int2 p[8];
        uint2 g[8];
#pragma unroll
        for (int j = 0; j < 8; ++j) p[j] = bk[k + j];
#pragma unroll
        for (int j = 0; j < 8; ++j) g[j] = hb[(size_t)p[j].x * 64 + lane];
#pragma unroll
        for (int j = 0; j < 8; ++j) {
            const float v = __int_as_float(p[j].y);
            acc.x = fmaf(bflo(g[j].x), v, acc.x);
            acc.y = fmaf(bfhi(g[j].x), v, acc.y);
            acc.z = fmaf(bflo(g[j].y), v, acc.z);
            acc.w = fmaf(bfhi(g[j].y), v, acc.w);
        }
    }
    for (; k < deg; ++k) {
        const int2 p = bk[k];
        const uint2 g = hb[(size_t)p.x * 64 + lane];
        const float v = __int_as_float(p.y);
        acc.x = fmaf(bflo(g.x), v, acc.x); acc.y = fmaf(bfhi(g.x), v, acc.y);
        acc.z = fmaf(bflo(g.y), v, acc.z); acc.w = fmaf(bfhi(g.y), v, acc.w);
    }

    if (FINAL) {
        const float s = 1.0f / 3.0f;
        acc.x = fmaxf(acc.x * s, 0.f);
        acc.y = fmaxf(acc.y * s, 0.f);
        acc.z = fmaxf(acc.z * s, 0.f);
        acc.w = fmaxf(acc.w * s, 0.f);
        ((float4*)outp)[(size_t)row * 64 + lane] = acc;
    } else {
        uint2 o;
        o.x = (unsigned int)f2bf_rtne(acc.x) | ((unsigned int)f2bf_rtne(acc.y) << 16);
        o.y = (unsigned int)f2bf_rtne(acc.z) | ((unsigned int)f2bf_rtne(acc.w) << 16);
        ((uint2*)outp)[(size_t)row * 64 + lane] = o;
    }
}

// ============ fallback tier: fp32 vector GEMM + fp32 bucket SPMM ============
__global__ __launch_bounds__(256) void bucket_only(const int* __restrict__ src,
                                                   const int* __restrict__ dst,
                                                   const float* __restrict__ vals,
                                                   int* __restrict__ counts,
                                                   int2* __restrict__ bucket, int E) {
    const int t = blockIdx.x * 256 + threadIdx.x;
    if (t < E) {
        const int d = dst[t];
        const int pos = atomicAdd(&counts[d], 1);
        if (pos < BUCKET)
            bucket[((size_t)d << 7) + pos] = make_int2(src[t], __float_as_int(vals[t]));
    }
}

__global__ __launch_bounds__(256) void gemm3_xw(const float* __restrict__ X,
                                                const float* __restrict__ W1,
                                                const float* __restrict__ W2,
                                                const float* __restrict__ W3,
                                                float* __restrict__ H1,
                                                float* __restrict__ H2,
                                                float* __restrict__ H3) {
    __shared__ float xs[GEMM_ROWS * F];
    const int tid = threadIdx.x;
    const int row0 = blockIdx.x * GEMM_ROWS;
#pragma unroll
    for (int r = 0; r < GEMM_ROWS; ++r)
        xs[r * F + tid] = X[(size_t)(row0 + r) * F + tid];
    __syncthreads();

    float a1[GEMM_ROWS], a2[GEMM_ROWS], a3[GEMM_ROWS];
#pragma unroll
    for (int r = 0; r < GEMM_ROWS; ++r) { a1[r] = 0.f; a2[r] = 0.f; a3[r] = 0.f; }

    const float4* xs4 = (const float4*)xs;
    for (int kk = 0; kk < F; kk += 4) {
        float w1v[4], w2v[4], w3v[4];
#pragma unroll
        for (int j = 0; j < 4; ++j) {
            w1v[j] = W1[(size_t)(kk + j) * F + tid];
            w2v[j] = W2[(size_t)(kk + j) * F + tid];
            w3v[j] = W3[(size_t)(kk + j) * F + tid];
        }
#pragma unroll
        for (int r = 0; r < GEMM_ROWS; ++r) {
            const float4 xv = xs4[r * NF4 + (kk >> 2)];
            a1[r] = fmaf(xv.x, w1v[0], a1[r]); a1[r] = fmaf(xv.y, w1v[1], a1[r]);
            a1[r] = fmaf(xv.z, w1v[2], a1[r]); a1[r] = fmaf(xv.w, w1v[3], a1[r]);
            a2[r] = fmaf(xv.x, w2v[0], a2[r]); a2[r] = fmaf(xv.y, w2v[1], a2[r]);
            a2[r] = fmaf(xv.z, w2v[2], a2[r]); a2[r] = fmaf(xv.w, w2v[3], a2[r]);
            a3[r] = fmaf(xv.x, w3v[0], a3[r]); a3[r] = fmaf(xv.y, w3v[1], a3[r]);
            a3[r] = fmaf(xv.z, w3v[2], a3[r]); a3[r] = fmaf(xv.w, w3v[3], a3[r]);
        }
    }
#pragma unroll
    for (int r = 0; r < GEMM_ROWS; ++r) {
        H1[(size_t)(row0 + r) * F + tid] = a1[r];
        H2[(size_t)(row0 + r) * F + tid] = a2[r];
        H3[(size_t)(row0 + r) * F + tid] = a3[r];
    }
}

// fp32 bucket SPMM (fallback): addv/out4 may alias row-locally — not restrict.
__global__ __launch_bounds__(256) void spmm_f32(const float4* __restrict__ h4,
                                                const int* __restrict__ counts,
                                                const int2* __restrict__ bucket,
                                                const float4* addv,
                                                float4* out4,
                                                int N, int final_mode) {
    const int row = (blockIdx.x * 256 + threadIdx.x) >> 6;
    const int lane = threadIdx.x & 63;
    if (row >= N) return;

    int deg = counts[row];
    deg = (deg > BUCKET) ? BUCKET : deg;
    const int2* bk = bucket + ((size_t)row << 7);

    float4 acc = addv ? addv[(size_t)row * 64 + lane]
                      : make_float4(0.f, 0.f, 0.f, 0.f);

    int k = 0;
    for (; k + 4 <= deg; k += 4) {
        const int2 p0 = bk[k + 0];
        const int2 p1 = bk[k + 1];
        const int2 p2 = bk[k + 2];
        const int2 p3 = bk[k + 3];
        const float4 h0 = h4[(size_t)p0.x * 64 + lane];
        const float4 h1 = h4[(size_t)p1.x * 64 + lane];
        const float4 h2 = h4[(size_t)p2.x * 64 + lane];
        const float4 h3 = h4[(size_t)p3.x * 64 + lane];
        const float v0 = __int_as_float(p0.y), v1 = __int_as_float(p1.y);
        const float v2 = __int_as_float(p2.y), v3 = __int_as_float(p3.y);
        acc.x = fmaf(h0.x, v0, acc.x); acc.y = fmaf(h0.y, v0, acc.y);
        acc.z = fmaf(h0.z, v0, acc.z); acc.w = fmaf(h0.w, v0, acc.w);
        acc.x = fmaf(h1.x, v1, acc.x); acc.y = fmaf(h1.y, v1, acc.y);
        acc.z = fmaf(h1.z, v1, acc.z); acc.w = fmaf(h1.w, v1, acc.w);
        acc.x = fmaf(h2.x, v2, acc.x); acc.y = fmaf(h2.y, v2, acc.y);
        acc.z = fmaf(h2.z, v2, acc.z); acc.w = fmaf(h2.w, v2, acc.w);
        acc.x = fmaf(h3.x, v3, acc.x); acc.y = fmaf(h3.y, v3, acc.y);
        acc.z = fmaf(h3.z, v3, acc.z); acc.w = fmaf(h3.w, v3, acc.w);
    }
    for (; k < deg; ++k) {
        const int2 p = bk[k];
        const float v = __int_as_float(p.y);
        const float4 hv = h4[(size_t)p.x * 64 + lane];
        acc.x = fmaf(hv.x, v, acc.x); acc.y = fmaf(hv.y, v, acc.y);
        acc.z = fmaf(hv.z, v, acc.z); acc.w = fmaf(hv.w, v, acc.w);
    }

    if (final_mode) {
        const float s = 1.0f / 3.0f;
        acc.x = fmaxf(acc.x * s, 0.f);
        acc.y = fmaxf(acc.y * s, 0.f);
        acc.z = fmaxf(acc.z * s, 0.f);
        acc.w = fmaxf(acc.w * s, 0.f);
    }
    out4[(size_t)row * 64 + lane] = acc;
}

extern "C" void kernel_launch(void* const* d_in, const int* in_sizes, int n_in,
                              void* d_out, int out_size, void* d_ws, size_t ws_size,
                              hipStream_t stream) {
    const float* x     = (const float*)d_in[0];
    const float* Avals = (const float*)d_in[1];
    const float* W1    = (const float*)d_in[2];
    const float* W2    = (const float*)d_in[3];
    const float* W3    = (const float*)d_in[4];
    const int*   esrc  = (const int*)d_in[5];
    const int*   edst  = (const int*)d_in[6];
    float*       out   = (float*)d_out;

    const int N = in_sizes[0] / F;   // 10000
    const int E = in_sizes[5];       // 320000

    const size_t mat_elems = (size_t)N * F;
    const int spmm_grid = ((size_t)N * 64 + 255) / 256;
    const int gemm_grid = (N + GEMM_ROWS - 1) / GEMM_ROWS;
    const int MT = N / 16;

    const size_t bucket_bytes = (size_t)N * BUCKET * sizeof(int2);   // 10.24 MB

    // tier-1: bucket + hb0..2 (bf16) + wpack + counts  (no xpack anymore)
    const size_t need_main =
        bucket_bytes + 3 * mat_elems * sizeof(short) +
        (size_t)3 * F * F * sizeof(short) + (size_t)(N + 16) * sizeof(int) + 64;
    const size_t need_fb =
        bucket_bytes + 2 * mat_elems * sizeof(float) + (size_t)(N + 16) * sizeof(int) + 64;

    if ((N % 16 == 0) && ws_size >= need_main) {
        int2*           bucket = (int2*)d_ws;
        unsigned short* hb0    = (unsigned short*)(bucket + (size_t)N * BUCKET);  // h3 / t2
        unsigned short* hb1    = hb0 + mat_elems;                                  // t1
        unsigned short* hb2    = hb1 + mat_elems;                                  // h2
        short*          wpack  = (short*)(hb2 + mat_elems);
        int*            counts = (int*)(wpack + (size_t)3 * F * F);

        hipMemsetAsync(counts, 0, (size_t)N * sizeof(int), stream);
        bucket_packw<<<(E + PW_THREADS + 255) / 256, 256, 0, stream>>>(
            esrc, edst, Avals, W1, W2, W3, counts, bucket, wpack, E);

        // h1 -> out (fp32), h2 -> hb2 (bf16), h3 -> hb0 (bf16); A read directly from x
        const int gw = 3 * MT * 4;
        mfma_gemm3<<<(gw * 64 + 255) / 256, 256, 0, stream>>>(x, wpack,
                                                              out, hb2, hb0, MT);

        // t1 = A h3 + h2 -> hb1 (bf16)
        spmm_bf<2, false><<<spmm_grid, 256, 0, stream>>>(
            (const uint2*)hb0, counts, bucket, hb2, hb1, N);
        // t2 = A t1 + h1 -> hb0 (bf16)
        spmm_bf<1, false><<<spmm_grid, 256, 0, stream>>>(
            (const uint2*)hb1, counts, bucket, out, hb0, N);
        // out = relu(A t2 / 3) -> fp32
        spmm_bf<0, true><<<spmm_grid, 256, 0, stream>>>(
            (const uint2*)hb0, counts, bucket, nullptr, out, N);
    } else if (ws_size >= need_fb) {
        int2*  bucket = (int2*)d_ws;
        float* h2buf  = (float*)(bucket + (size_t)N * BUCKET);
        float* h3buf  = h2buf + mat_elems;
        int*   counts = (int*)(h3buf + mat_elems);

        hipMemsetAsync(counts, 0, (size_t)N * sizeof(int), stream);
        bucket_only<<<(E + 255) / 256, 256, 0, stream>>>(esrc, edst, Avals,
                                                         counts, bucket, E);

        gemm3_xw<<<gemm_grid, 256, 0, stream>>>(x, W1, W2, W3, out, h2buf, h3buf);

        spmm_f32<<<spmm_grid, 256, 0, stream>>>((const float4*)h3buf, counts, bucket,
                                                (const float4*)h2buf, (float4*)h2buf, N, 0);
        spmm_f32<<<spmm_grid, 256, 0, stream>>>((const float4*)h2buf, counts, bucket,
                                                (const float4*)out, (float4*)h3buf, N, 0);
        spmm_f32<<<spmm_grid, 256, 0, stream>>>((const float4*)h3buf, counts, bucket,
                                                nullptr, (float4*)out, N, 1);
    }
}

// Round 12
// 113.112 us; speedup vs baseline: 1.3513x; 1.1144x over previous
//
#include <hip/hip_runtime.h>
#include <hip/hip_bf16.h>

#define F 256
#define NF4 (F / 4)
#define GEMM_ROWS 16
#define BUCKET 128
#define PW_THREADS (3 * 8 * 16 * 64)   // 24576

typedef short v8s __attribute__((ext_vector_type(8)));
typedef float v4f __attribute__((ext_vector_type(4)));

__device__ __forceinline__ unsigned short f2bf_rtne(float f) {
    unsigned int u = __float_as_uint(f);
    u += 0x7FFFu + ((u >> 16) & 1u);
    return (unsigned short)(u >> 16);
}
__device__ __forceinline__ float bflo(unsigned int u) { return __uint_as_float(u << 16); }
__device__ __forceinline__ float bfhi(unsigned int u) { return __uint_as_float(u & 0xFFFF0000u); }

// ============ fused: bucket-scatter (count+placement in one atomic) + pack_x + pack_w ====
// counts pre-zeroed. bucket[d*128+pos] = {src, val}.
// xpack: [mtile][ks][lane][j] bf16 = x[mtile*16+(lane&15)][ks*32+(lane>>4)*8+j]
// wpack: [mat][ks][ntile][lane][j] bf16 = W[ks*32+(lane>>4)*8+j][ntile*16+(lane&15)]
__global__ __launch_bounds__(256) void pack_bucket(const float* __restrict__ X,
                                                   const float* __restrict__ W1,
                                                   const float* __restrict__ W2,
                                                   const float* __restrict__ W3,
                                                   const int* __restrict__ src,
                                                   const int* __restrict__ dst,
                                                   const float* __restrict__ vals,
                                                   int* __restrict__ counts,
                                                   int2* __restrict__ bucket,
                                                   short* __restrict__ xpack,
                                                   short* __restrict__ wpack,
                                                   int MT, int E) {
    const int t = blockIdx.x * 256 + threadIdx.x;
    if (t < E) {
        const int d = dst[t];
        const int pos = atomicAdd(&counts[d], 1);
        if (pos < BUCKET)   // memory-safety only; never triggers (max deg ~56)
            bucket[((size_t)d << 7) + pos] = make_int2(src[t], __float_as_int(vals[t]));
        return;
    }
    const int u = t - E;
    const int PX = MT * 8 * 64;
    if (u < PX) {
        const int lane = u & 63;
        const int ks = (u >> 6) & 7;
        const int mtile = u >> 9;
        const int row = mtile * 16 + (lane & 15);
        const int kbase = ks * 32 + ((lane >> 4) << 3);
        const float* srcp = X + (size_t)row * F + kbase;
        v8s o;
#pragma unroll
        for (int j = 0; j < 8; ++j) o[j] = (short)f2bf_rtne(srcp[j]);
        ((v8s*)xpack)[u] = o;
    } else if (u < PX + PW_THREADS) {
        const int tw = u - PX;
        const int lane = tw & 63;
        const int nt = (tw >> 6) & 15;
        const int ks = (tw >> 10) & 7;
        const int mat = tw >> 13;
        const float* W = (mat == 0) ? W1 : (mat == 1 ? W2 : W3);
        const int col = nt * 16 + (lane & 15);
        const int kbase = ks * 32 + ((lane >> 4) << 3);
        v8s o;
#pragma unroll
        for (int j = 0; j < 8; ++j) o[j] = (short)f2bf_rtne(W[(size_t)(kbase + j) * F + col]);
        ((v8s*)wpack)[tw] = o;
    }
}

// ============ MFMA GEMM, 2 mtiles per wave (B-fragment reuse x2) ============
// H1 fp32 (=out), H2 bf16, H3 bf16. MT may be odd: last pair duplicates m0's
// compute into slot 1 and guards the store.
__global__ __launch_bounds__(256) void mfma_gemm3(const short* __restrict__ xpack,
                                                  const short* __restrict__ wpack,
                                                  float* __restrict__ H1,
                                                  unsigned short* __restrict__ H2b,
                                                  unsigned short* __restrict__ H3b,
                                                  int MT, int MP) {
    const int wid = (blockIdx.x * 256 + threadIdx.x) >> 6;
    const int lane = threadIdx.x & 63;
    const int per_mat = MP * 4;
    if (wid >= 3 * per_mat) return;
    const int mat = wid / per_mat;
    const int rem = wid - mat * per_mat;
    const int mp = rem >> 2;
    const int ntq = rem & 3;

    const int m0 = 2 * mp;
    const bool has2 = (m0 + 1) < MT;
    const int m1 = has2 ? (m0 + 1) : m0;

    const v8s* xa0 = (const v8s*)xpack + (size_t)m0 * (8 * 64) + lane;
    const v8s* xa1 = (const v8s*)xpack + (size_t)m1 * (8 * 64) + lane;
    const v8s* wb = (const v8s*)wpack + (size_t)mat * (8 * 16 * 64) + ntq * (4 * 64) + lane;

    v8s a0[8], a1[8];
#pragma unroll
    for (int ks = 0; ks < 8; ++ks) { a0[ks] = xa0[ks * 64]; a1[ks] = xa1[ks * 64]; }

    v4f acc0[4], acc1[4];
#pragma unroll
    for (int nt = 0; nt < 4; ++nt) {
        v4f z = {0.f, 0.f, 0.f, 0.f};
        acc0[nt] = z; acc1[nt] = z;
    }

#pragma unroll
    for (int ks = 0; ks < 8; ++ks)
#pragma unroll
        for (int nt = 0; nt < 4; ++nt) {
            const v8s b = wb[ks * (16 * 64) + nt * 64];   // loaded once, used twice
            acc0[nt] = __builtin_amdgcn_mfma_f32_16x16x32_bf16(a0[ks], b, acc0[nt], 0, 0, 0);
            acc1[nt] = __builtin_amdgcn_mfma_f32_16x16x32_bf16(a1[ks], b, acc1[nt], 0, 0, 0);
        }

    const int rbase = ((lane >> 4) << 2);   // C/D: row=(lane>>4)*4+reg
    const int c0 = ntq * 64 + (lane & 15);  //      col=lane&15
#pragma unroll
    for (int m = 0; m < 2; ++m) {
        if (m == 1 && !has2) continue;
        const int r0 = (m0 + m) * 16 + rbase;
        if (mat == 0) {
#pragma unroll
            for (int nt = 0; nt < 4; ++nt)
#pragma unroll
                for (int reg = 0; reg < 4; ++reg)
                    H1[(size_t)(r0 + reg) * F + c0 + nt * 16] =
                        (m == 0) ? acc0[nt][reg] : acc1[nt][reg];
        } else {
            unsigned short* H = (mat == 1) ? H2b : H3b;
#pragma unroll
            for (int nt = 0; nt < 4; ++nt)
#pragma unroll
                for (int reg = 0; reg < 4; ++reg)
                    H[(size_t)(r0 + reg) * F + c0 + nt * 16] =
                        f2bf_rtne((m == 0) ? acc0[nt][reg] : acc1[nt][reg]);
        }
    }
}

// ============ SPMM: one wave per row, bf16 gathers (512B/wave), unroll-8 — R7 proven ====
// ADD_MODE: 0=none, 1=fp32 addv, 2=bf16 addv. FINAL: relu(acc/3)->fp32, else bf16.
template <int ADD_MODE, bool FINAL>
__global__ __launch_bounds__(256) void spmm_bf(const uint2* __restrict__ hb,
                                               const int* __restrict__ counts,
                                               const int2* __restrict__ bucket,
                                               const void* __restrict__ addv,
                                               void* __restrict__ outp, int N) {
    const int row = (blockIdx.x * 256 + threadIdx.x) >> 6;
    const int lane = threadIdx.x & 63;
    if (row >= N) return;

    int deg = counts[row];
    deg = (deg > BUCKET) ? BUCKET : deg;
    const int2* bk = bucket + ((size_t)row << 7);

    float4 acc;
    if (ADD_MODE == 1) {
        acc = ((const float4*)addv)[(size_t)row * 64 + lane];
    } else if (ADD_MODE == 2) {
        const uint2 a = ((const uint2*)addv)[(size_t)row * 64 + lane];
        acc = make_float4(bflo(a.x), bfhi(a.x), bflo(a.y), bfhi(a.y));
    } else {
        acc = make_float4(0.f, 0.f, 0.f, 0.f);
    }

    int k = 0;
    for (; k + 8 <= deg; k += 8) {
        int2 p[8];
        uint2 g[8];
#pragma unroll
        for (int j = 0; j < 8; ++j) p[j] = bk[k + j];
#pragma unroll
        for (int j = 0; j < 8; ++j) g[j] = hb[(size_t)p[j].x * 64 + lane];
#pragma unroll
        for (int j = 0; j < 8; ++j) {
            const float v = __int_as_float(p[j].y);
            acc.x = fmaf(bflo(g[j].x), v, acc.x);
            acc.y = fmaf(bfhi(g[j].x), v, acc.y);
            acc.z = fmaf(bflo(g[j].y), v, acc.z);
            acc.w = fmaf(bfhi(g[j].y), v, acc.w);
        }
    }
    for (; k < deg; ++k) {
        const int2 p = bk[k];
        const uint2 g = hb[(size_t)p.x * 64 + lane];
        const float v = __int_as_float(p.y);
        acc.x = fmaf(bflo(g.x), v, acc.x); acc.y = fmaf(bfhi(g.x), v, acc.y);
        acc.z = fmaf(bflo(g.y), v, acc.z); acc.w = fmaf(bfhi(g.y), v, acc.w);
    }

    if (FINAL) {
        const float s = 1.0f / 3.0f;
        acc.x = fmaxf(acc.x * s, 0.f);
        acc.y = fmaxf(acc.y * s, 0.f);
        acc.z = fmaxf(acc.z * s, 0.f);
        acc.w = fmaxf(acc.w * s, 0.f);
        ((float4*)outp)[(size_t)row * 64 + lane] = acc;
    } else {
        uint2 o;
        o.x = (unsigned int)f2bf_rtne(acc.x) | ((unsigned int)f2bf_rtne(acc.y) << 16);
        o.y = (unsigned int)f2bf_rtne(acc.z) | ((unsigned int)f2bf_rtne(acc.w) << 16);
        ((uint2*)outp)[(size_t)row * 64 + lane] = o;
    }
}

// ============ fallback tier: fp32 vector GEMM + fp32 bucket SPMM ============
__global__ __launch_bounds__(256) void bucket_only(const int* __restrict__ src,
                                                   const int* __restrict__ dst,
                                                   const float* __restrict__ vals,
                                                   int* __restrict__ counts,
                                                   int2* __restrict__ bucket, int E) {
    const int t = blockIdx.x * 256 + threadIdx.x;
    if (t < E) {
        const int d = dst[t];
        const int pos = atomicAdd(&counts[d], 1);
        if (pos < BUCKET)
            bucket[((size_t)d << 7) + pos] = make_int2(src[t], __float_as_int(vals[t]));
    }
}

__global__ __launch_bounds__(256) void gemm3_xw(const float* __restrict__ X,
                                                const float* __restrict__ W1,
                                                const float* __restrict__ W2,
                                                const float* __restrict__ W3,
                                                float* __restrict__ H1,
                                                float* __restrict__ H2,
                                                float* __restrict__ H3) {
    __shared__ float xs[GEMM_ROWS * F];
    const int tid = threadIdx.x;
    const int row0 = blockIdx.x * GEMM_ROWS;
#pragma unroll
    for (int r = 0; r < GEMM_ROWS; ++r)
        xs[r * F + tid] = X[(size_t)(row0 + r) * F + tid];
    __syncthreads();

    float a1[GEMM_ROWS], a2[GEMM_ROWS], a3[GEMM_ROWS];
#pragma unroll
    for (int r = 0; r < GEMM_ROWS; ++r) { a1[r] = 0.f; a2[r] = 0.f; a3[r] = 0.f; }

    const float4* xs4 = (const float4*)xs;
    for (int kk = 0; kk < F; kk += 4) {
        float w1v[4], w2v[4], w3v[4];
#pragma unroll
        for (int j = 0; j < 4; ++j) {
            w1v[j] = W1[(size_t)(kk + j) * F + tid];
            w2v[j] = W2[(size_t)(kk + j) * F + tid];
            w3v[j] = W3[(size_t)(kk + j) * F + tid];
        }
#pragma unroll
        for (int r = 0; r < GEMM_ROWS; ++r) {
            const float4 xv = xs4[r * NF4 + (kk >> 2)];
            a1[r] = fmaf(xv.x, w1v[0], a1[r]); a1[r] = fmaf(xv.y, w1v[1], a1[r]);
            a1[r] = fmaf(xv.z, w1v[2], a1[r]); a1[r] = fmaf(xv.w, w1v[3], a1[r]);
            a2[r] = fmaf(xv.x, w2v[0], a2[r]); a2[r] = fmaf(xv.y, w2v[1], a2[r]);
            a2[r] = fmaf(xv.z, w2v[2], a2[r]); a2[r] = fmaf(xv.w, w2v[3], a2[r]);
            a3[r] = fmaf(xv.x, w3v[0], a3[r]); a3[r] = fmaf(xv.y, w3v[1], a3[r]);
            a3[r] = fmaf(xv.z, w3v[2], a3[r]); a3[r] = fmaf(xv.w, w3v[3], a3[r]);
        }
    }
#pragma unroll
    for (int r = 0; r < GEMM_ROWS; ++r) {
        H1[(size_t)(row0 + r) * F + tid] = a1[r];
        H2[(size_t)(row0 + r) * F + tid] = a2[r];
        H3[(size_t)(row0 + r) * F + tid] = a3[r];
    }
}

// fp32 bucket SPMM (fallback): addv/out4 may alias row-locally — not restrict.
__global__ __launch_bounds__(256) void spmm_f32(const float4* __restrict__ h4,
                                                const int* __restrict__ counts,
                                                const int2* __restrict__ bucket,
                                                const float4* addv,
                                                float4* out4,
                                                int N, int final_mode) {
    const int row = (blockIdx.x * 256 + threadIdx.x) >> 6;
    const int lane = threadIdx.x & 63;
    if (row >= N) return;

    int deg = counts[row];
    deg = (deg > BUCKET) ? BUCKET : deg;
    const int2* bk = bucket + ((size_t)row << 7);

    float4 acc = addv ? addv[(size_t)row * 64 + lane]
                      : make_float4(0.f, 0.f, 0.f, 0.f);

    int k = 0;
    for (; k + 4 <= deg; k += 4) {
        const int2 p0 = bk[k + 0];
        const int2 p1 = bk[k + 1];
        const int2 p2 = bk[k + 2];
        const int2 p3 = bk[k + 3];
        const float4 h0 = h4[(size_t)p0.x * 64 + lane];
        const float4 h1 = h4[(size_t)p1.x * 64 + lane];
        const float4 h2 = h4[(size_t)p2.x * 64 + lane];
        const float4 h3 = h4[(size_t)p3.x * 64 + lane];
        const float v0 = __int_as_float(p0.y), v1 = __int_as_float(p1.y);
        const float v2 = __int_as_float(p2.y), v3 = __int_as_float(p3.y);
        acc.x = fmaf(h0.x, v0, acc.x); acc.y = fmaf(h0.y, v0, acc.y);
        acc.z = fmaf(h0.z, v0, acc.z); acc.w = fmaf(h0.w, v0, acc.w);
        acc.x = fmaf(h1.x, v1, acc.x); acc.y = fmaf(h1.y, v1, acc.y);
        acc.z = fmaf(h1.z, v1, acc.z); acc.w = fmaf(h1.w, v1, acc.w);
        acc.x = fmaf(h2.x, v2, acc.x); acc.y = fmaf(h2.y, v2, acc.y);
        acc.z = fmaf(h2.z, v2, acc.z); acc.w = fmaf(h2.w, v2, acc.w);
        acc.x = fmaf(h3.x, v3, acc.x); acc.y = fmaf(h3.y, v3, acc.y);
        acc.z = fmaf(h3.z, v3, acc.z); acc.w = fmaf(h3.w, v3, acc.w);
    }
    for (; k < deg; ++k) {
        const int2 p = bk[k];
        const float v = __int_as_float(p.y);
        const float4 hv = h4[(size_t)p.x * 64 + lane];
        acc.x = fmaf(hv.x, v, acc.x); acc.y = fmaf(hv.y, v, acc.y);
        acc.z = fmaf(hv.z, v, acc.z); acc.w = fmaf(hv.w, v, acc.w);
    }

    if (final_mode) {
        const float s = 1.0f / 3.0f;
        acc.x = fmaxf(acc.x * s, 0.f);
        acc.y = fmaxf(acc.y * s, 0.f);
        acc.z = fmaxf(acc.z * s, 0.f);
        acc.w = fmaxf(acc.w * s, 0.f);
    }
    out4[(size_t)row * 64 + lane] = acc;
}

extern "C" void kernel_launch(void* const* d_in, const int* in_sizes, int n_in,
                              void* d_out, int out_size, void* d_ws, size_t ws_size,
                              hipStream_t stream) {
    const float* x     = (const float*)d_in[0];
    const float* Avals = (const float*)d_in[1];
    const float* W1    = (const float*)d_in[2];
    const float* W2    = (const float*)d_in[3];
    const float* W3    = (const float*)d_in[4];
    const int*   esrc  = (const int*)d_in[5];
    const int*   edst  = (const int*)d_in[6];
    float*       out   = (float*)d_out;

    const int N = in_sizes[0] / F;   // 10000
    const int E = in_sizes[5];       // 320000

    const size_t mat_elems = (size_t)N * F;
    const int spmm_grid = ((size_t)N * 64 + 255) / 256;
    const int gemm_grid = (N + GEMM_ROWS - 1) / GEMM_ROWS;
    const int MT = N / 16;
    const int MP = (MT + 1) / 2;

    const size_t bucket_bytes = (size_t)N * BUCKET * sizeof(int2);   // 10.24 MB

    // tier-1: bucket + hb0..2 + xpack (bf16) + wpack + counts
    const size_t need_main =
        bucket_bytes + 4 * mat_elems * sizeof(short) +
        (size_t)3 * F * F * sizeof(short) + (size_t)(N + 16) * sizeof(int) + 64;
    const size_t need_fb =
        bucket_bytes + 2 * mat_elems * sizeof(float) + (size_t)(N + 16) * sizeof(int) + 64;

    if ((N % 16 == 0) && ws_size >= need_main) {
        int2*           bucket = (int2*)d_ws;
        unsigned short* hb0    = (unsigned short*)(bucket + (size_t)N * BUCKET);  // h3 / t2
        unsigned short* hb1    = hb0 + mat_elems;                                  // t1
        unsigned short* hb2    = hb1 + mat_elems;                                  // h2
        short*          xpack  = (short*)(hb2 + mat_elems);
        short*          wpack  = xpack + mat_elems;
        int*            counts = (int*)(wpack + (size_t)3 * F * F);

        const int PX = MT * 8 * 64;
        const int pc_threads = E + PX + PW_THREADS;

        hipMemsetAsync(counts, 0, (size_t)N * sizeof(int), stream);
        pack_bucket<<<(pc_threads + 255) / 256, 256, 0, stream>>>(
            x, W1, W2, W3, esrc, edst, Avals, counts, bucket, xpack, wpack, MT, E);

        // h1 -> out (fp32), h2 -> hb2 (bf16), h3 -> hb0 (bf16); 2 mtiles/wave
        const int gw = 3 * MP * 4;
        mfma_gemm3<<<(gw * 64 + 255) / 256, 256, 0, stream>>>(xpack, wpack,
                                                              out, hb2, hb0, MT, MP);

        // t1 = A h3 + h2 -> hb1 (bf16)
        spmm_bf<2, false><<<spmm_grid, 256, 0, stream>>>(
            (const uint2*)hb0, counts, bucket, hb2, hb1, N);
        // t2 = A t1 + h1 -> hb0 (bf16)
        spmm_bf<1, false><<<spmm_grid, 256, 0, stream>>>(
            (const uint2*)hb1, counts, bucket, out, hb0, N);
        // out = relu(A t2 / 3) -> fp32
        spmm_bf<0, true><<<spmm_grid, 256, 0, stream>>>(
            (const uint2*)hb0, counts, bucket, nullptr, out, N);
    } else if (ws_size >= need_fb) {
        int2*  bucket = (int2*)d_ws;
        float* h2buf  = (float*)(bucket + (size_t)N * BUCKET);
        float* h3buf  = h2buf + mat_elems;
        int*   counts = (int*)(h3buf + mat_elems);

        hipMemsetAsync(counts, 0, (size_t)N * sizeof(int), stream);
        bucket_only<<<(E + 255) / 256, 256, 0, stream>>>(esrc, edst, Avals,
                                                         counts, bucket, E);

        gemm3_xw<<<gemm_grid, 256, 0, stream>>>(x, W1, W2, W3, out, h2buf, h3buf);

        spmm_f32<<<spmm_grid, 256, 0, stream>>>((const float4*)h3buf, counts, bucket,
                                                (const float4*)h2buf, (float4*)h2buf, N, 0);
        spmm_f32<<<spmm_grid, 256, 0, stream>>>((const float4*)h2buf, counts, bucket,
                                                (const float4*)out, (float4*)h3buf, N, 0);
        spmm_f32<<<spmm_grid, 256, 0, stream>>>((const float4*)h3buf, counts, bucket,
                                                nullptr, (float4*)out, N, 1);
    }
}